// Round 3
// baseline (134.969 us; speedup 1.0000x reference)
//
#include <hip/hip_runtime.h>
#include <cmath>

#define S_SUB 512
#define T_TR  8192
#define D_IN  8
#define NSEG  4            // segments per subject
#define SEGT  (T_TR/NSEG)  // 2048 trials per segment
#define BLK   256          // threads per block
#define CH    (SEGT/BLK)   // 8 trials per thread
#define NW    (BLK/64)     // 4 waves per block

typedef float f4 __attribute__((ext_vector_type(4)));

// ---------------------------------------------------------------------------
// Per-subject parameter chain (f64, identical math to the validated kernel).
// Fa = Phi(-9.9), dF = Phi(0.1)-Phi(-9.9) are computed on the HOST (input-
// independent constants) and passed by value.
// ---------------------------------------------------------------------------
__device__ __forceinline__ void param_chain(double Fa, double dF,
    float ua, float sq, float emu, float ex0,
    double& a, double& b, double& sd, double& x0)
{
    const double RS2 = 0.7071067811865476;     // 1/sqrt(2)
    const double S2  = 1.4142135623730951;     // sqrt(2)
    const double ISQ = 0.3989422804014327;     // 1/sqrt(2*pi)
    double p = fma((double)ua, dF, Fa);
    double z = -S2 * erfcinv(2.0 * p);
    #pragma unroll
    for (int it = 0; it < 2; ++it) {           // Newton polish: Phi(z)=p
        double F   = 0.5 * erfc(-z * RS2);
        double pdf = exp(-0.5 * z * z) * ISQ;
        z -= (F - p) / pdf;
    }
    a  = 0.99 + 0.1 * z;
    double mu = (double)emu;
    b  = mu * (1.0 - a);
    x0 = mu + (double)ex0;
    sd = sqrt((double)sq);
}

// ---------------------------------------------------------------------------
// Kernel 1: per-(subject,segment) affine compose of x_{t+1} = a x_t + c_t.
// Wave 0 computes the param chain (hidden under the eps_x loads), broadcasts
// via LDS; seg==0 blocks persist params for the fused kernel. Segment total
// via 6-step ordered shfl_down wave reduce + tiny LDS cross-wave compose.
// seg==3's composition is never consumed -> early exit.
// ---------------------------------------------------------------------------
__global__ __launch_bounds__(BLK) void compose_kernel(
    const float* __restrict__ eps_x,
    const float* __restrict__ u_a,
    const float* __restrict__ sigmasq,
    const float* __restrict__ eps_mu,
    const float* __restrict__ eps_x0,
    double Fa, double dF,
    double2* __restrict__ comp,       // [NSEG-1][S]
    double* __restrict__ params)      // [S][4] = a,b,sd,x0
{
    const int bid = blockIdx.x;
    const int s   = bid >> 2;
    const int seg = bid & 3;
    if (seg == NSEG - 1) return;
    const int tid  = threadIdx.x;
    const int lane = tid & 63;
    const int wid  = tid >> 6;

    __shared__ double  pl[3];
    __shared__ double2 wtot[NW];

    const size_t base = (size_t)s * T_TR + (size_t)seg * SEGT + (size_t)tid * CH;

    // issue loads first so the param chain hides under them
    const f4* e4 = (const f4*)(eps_x + base);
    f4 v0 = e4[0];
    f4 v1 = e4[1];

    if (tid < 64) {
        double a, b, sd, x0;
        param_chain(Fa, dF, u_a[s], sigmasq[s], eps_mu[s], eps_x0[s], a, b, sd, x0);
        if (tid == 0) {
            pl[0] = a; pl[1] = b; pl[2] = sd;
            if (seg == 0) {
                params[4*s+0] = a;  params[4*s+1] = b;
                params[4*s+2] = sd; params[4*s+3] = x0;
            }
        }
    }
    __syncthreads();
    const double a = pl[0], b = pl[1], sd = pl[2];

    float ev[CH];
    ev[0]=v0.x; ev[1]=v0.y; ev[2]=v0.z; ev[3]=v0.w;
    ev[4]=v1.x; ev[5]=v1.y; ev[6]=v1.z; ev[7]=v1.w;

    double A = 1.0, Bv = 0.0;
    #pragma unroll
    for (int j = 0; j < CH; ++j) {
        double c = fma(sd, (double)ev[j], b);
        Bv = fma(a, Bv, c);
        A *= a;
    }

    // ordered wave reduce (earliest lane first); lane 0 holds wave total
    #pragma unroll
    for (int off = 1; off < 64; off <<= 1) {
        double pA = __shfl_down(A, off);
        double pB = __shfl_down(Bv, off);
        Bv = fma(pA, Bv, pB);     // later ∘ earlier
        A  = pA * A;
    }
    if (lane == 0) wtot[wid] = make_double2(A, Bv);
    __syncthreads();
    if (tid == 0) {
        double CA = wtot[0].x, CB = wtot[0].y;
        #pragma unroll
        for (int w = 1; w < NW; ++w) {
            CB = fma(wtot[w].x, CB, wtot[w].y);
            CA = wtot[w].x * CA;
        }
        comp[seg * S_SUB + s] = make_double2(CA, CB);
    }
}

// ---------------------------------------------------------------------------
// Kernel 2: fused seed-chain + per-segment scan + replay + logits + Bernoulli.
// Seed: x0 advanced through <=3 segment composes (L2-hot, block-uniform).
// Scan: 6-step shfl_up wave scan + cross-wave prefix via 64B LDS (2 barriers).
// Phase 3 math identical (f64) to the validated round-1/2 kernel.
// inputs are strictly single-use -> non-temporal loads; outputs nt stores.
// ---------------------------------------------------------------------------
__global__ __launch_bounds__(BLK) void fused_kernel(
    const float* __restrict__ inputs,
    const float* __restrict__ eps_w,
    const float* __restrict__ eps_x,
    const float* __restrict__ u_bern,
    const double* __restrict__ params,
    const double2* __restrict__ comp,
    float* __restrict__ out_x,
    float* __restrict__ out_y)
{
    const int bid  = blockIdx.x;
    const int s    = bid >> 2;
    const int seg  = bid & 3;
    const int tid  = threadIdx.x;
    const int lane = tid & 63;
    const int wid  = tid >> 6;

    __shared__ double2 wtot[NW];

    const size_t base = (size_t)s * T_TR + (size_t)seg * SEGT + (size_t)tid * CH;

    // issue streaming loads early
    const f4* e4 = (const f4*)(eps_x + base);
    f4 ev0 = e4[0];
    f4 ev1 = e4[1];
    const f4* u4 = (const f4*)(u_bern + base);
    f4 ub0 = u4[0];
    f4 ub1 = u4[1];

    // block-uniform parameters + inline seed chain
    const double a  = params[4*s+0];
    const double b  = params[4*s+1];
    const double sd = params[4*s+2];
    double xseed    = params[4*s+3];
    for (int i = 0; i < seg; ++i) {
        double2 c = comp[i * S_SUB + s];
        xseed = fma(c.x, xseed, c.y);
    }

    const float* wp = eps_w + s * D_IN;
    const double w0 = (double)wp[0], w1 = (double)wp[1];
    const double w2 = (double)wp[2], w3 = (double)wp[3];
    const double w4 = (double)wp[4], w5 = (double)wp[5];
    const double w6 = (double)wp[6], w7 = (double)wp[7];

    float ev[CH];
    ev[0]=ev0.x; ev[1]=ev0.y; ev[2]=ev0.z; ev[3]=ev0.w;
    ev[4]=ev1.x; ev[5]=ev1.y; ev[6]=ev1.z; ev[7]=ev1.w;
    float ubv[CH];
    ubv[0]=ub0.x; ubv[1]=ub0.y; ubv[2]=ub0.z; ubv[3]=ub0.w;
    ubv[4]=ub1.x; ubv[5]=ub1.y; ubv[6]=ub1.z; ubv[7]=ub1.w;

    // phase 1: local affine compose over the chunk
    double A = 1.0, Bv = 0.0;
    #pragma unroll
    for (int j = 0; j < CH; ++j) {
        double c = fma(sd, (double)ev[j], b);
        Bv = fma(a, Bv, c);
        A *= a;
    }

    // phase 2a: inclusive wave scan (ordered Hillis-Steele via shfl_up)
    #pragma unroll
    for (int off = 1; off < 64; off <<= 1) {
        double pA = __shfl_up(A, off);
        double pB = __shfl_up(Bv, off);
        if (lane >= off) {
            Bv = fma(A, pB, Bv);   // cur ∘ prev
            A  = A * pA;
        }
    }
    if (lane == 63) wtot[wid] = make_double2(A, Bv);
    __syncthreads();

    // phase 2b: exclusive cross-wave prefix P = waves 0..wid-1 composed
    double PA = 1.0, PB = 0.0;
    for (int w = 0; w < wid; ++w) {
        double2 t = wtot[w];
        PB = fma(t.x, PB, t.y);
        PA = t.x * PA;
    }
    // per-thread exclusive map = (prev lane's inclusive) ∘ P
    double eA = __shfl_up(A, 1);
    double eB = __shfl_up(Bv, 1);
    if (lane == 0) { eA = 1.0; eB = 0.0; }
    double EB = fma(eA, PB, eB);
    double EA = eA * PA;
    double x  = fma(EA, xseed, EB);   // x at start of this thread's chunk

    // phase 3: replay chunk, fuse logits + Bernoulli (f64, unchanged math)
    const f4* in4 = (const f4*)(inputs + base * D_IN);
    float xv[CH], yv[CH];
    #pragma unroll
    for (int j = 0; j < CH; ++j) {
        f4 i0 = __builtin_nontemporal_load(in4 + 2*j);
        f4 i1 = __builtin_nontemporal_load(in4 + 2*j + 1);
        double dot = fma((double)i0.x, w0,
                     fma((double)i0.y, w1,
                     fma((double)i0.z, w2,
                     fma((double)i0.w, w3,
                     fma((double)i1.x, w4,
                     fma((double)i1.y, w5,
                     fma((double)i1.z, w6, (double)i1.w * w7)))))));
        double L = x + dot;
        double E = exp(-L);
        yv[j] = ((double)ubv[j] * (1.0 + E) < 1.0) ? 1.0f : 0.0f;
        xv[j] = (float)x;
        double c = fma(sd, (double)ev[j], b);
        x = fma(a, x, c);
    }

    f4* ox = (f4*)(out_x + base);
    f4* oy = (f4*)(out_y + base);
    #pragma unroll
    for (int q = 0; q < CH/4; ++q) {
        f4 vx; vx.x=xv[4*q+0]; vx.y=xv[4*q+1]; vx.z=xv[4*q+2]; vx.w=xv[4*q+3];
        f4 vy; vy.x=yv[4*q+0]; vy.y=yv[4*q+1]; vy.z=yv[4*q+2]; vy.w=yv[4*q+3];
        __builtin_nontemporal_store(vx, ox + q);
        __builtin_nontemporal_store(vy, oy + q);
    }
}

extern "C" void kernel_launch(void* const* d_in, const int* in_sizes, int n_in,
                              void* d_out, int out_size, void* d_ws, size_t ws_size,
                              hipStream_t stream) {
    const float* inputs  = (const float*)d_in[0];   // [S,T,D]
    const float* eps_w   = (const float*)d_in[1];   // [S,D]
    const float* u_a     = (const float*)d_in[2];   // [S]
    const float* sigmasq = (const float*)d_in[3];   // [S]
    const float* eps_mu  = (const float*)d_in[4];   // [S]
    const float* eps_x0  = (const float*)d_in[5];   // [S]
    const float* eps_x   = (const float*)d_in[6];   // [S,T]
    const float* u_bern  = (const float*)d_in[7];   // [S,T]

    float* out = (float*)d_out;                     // [x | y] f32

    double*  params = (double*)d_ws;                          // 16 KiB
    double2* comp   = (double2*)((char*)d_ws + 16*1024);      // 24 KiB used

    // input-independent truncation constants, computed on host (f64 libm)
    const double RS2 = 0.7071067811865476;
    const double Fa  = 0.5 * erfc(9.9 * RS2);       // Phi(-9.9)
    const double Fb  = 0.5 * erfc(-0.1 * RS2);      // Phi(0.1)
    const double dF  = Fb - Fa;

    compose_kernel<<<S_SUB*NSEG, BLK, 0, stream>>>(eps_x, u_a, sigmasq, eps_mu,
                                                   eps_x0, Fa, dF, comp, params);
    fused_kernel<<<S_SUB*NSEG, BLK, 0, stream>>>(inputs, eps_w, eps_x, u_bern,
                                                 params, comp,
                                                 out, out + (size_t)S_SUB * T_TR);
}

// Round 4
// 41.116 us; speedup vs baseline: 3.2826x; 3.2826x over previous
//
#include <hip/hip_runtime.h>
#include <cmath>

#define S_SUB 512
#define T_TR  8192
#define D_IN  8
#define NSEG  4            // segments per subject
#define SEGT  (T_TR/NSEG)  // 2048 trials per segment
#define BLK   256          // threads per block
#define CH    (SEGT/BLK)   // 8 trials per thread
#define NW    (BLK/64)     // 4 waves per block

typedef float f4 __attribute__((ext_vector_type(4)));

// ---------------------------------------------------------------------------
// Per-subject parameter chain (f64). Fa = Phi(-9.9), dF = Phi(0.1)-Phi(-9.9)
// are host-computed constants passed by value.
// ---------------------------------------------------------------------------
__device__ __forceinline__ void param_chain(double Fa, double dF,
    float ua, float sq, float emu, float ex0,
    double& a, double& b, double& sd, double& x0)
{
    const double RS2 = 0.7071067811865476;     // 1/sqrt(2)
    const double S2  = 1.4142135623730951;     // sqrt(2)
    const double ISQ = 0.3989422804014327;     // 1/sqrt(2*pi)
    double p = fma((double)ua, dF, Fa);
    double z = -S2 * erfcinv(2.0 * p);
    #pragma unroll
    for (int it = 0; it < 2; ++it) {           // Newton polish: Phi(z)=p
        double F   = 0.5 * erfc(-z * RS2);
        double pdf = exp(-0.5 * z * z) * ISQ;
        z -= (F - p) / pdf;
    }
    a  = 0.99 + 0.1 * z;
    double mu = (double)emu;
    b  = mu * (1.0 - a);
    x0 = mu + (double)ex0;
    sd = sqrt((double)sq);
}

// ---------------------------------------------------------------------------
// Kernel 1: per-(subject,segment) affine compose of x_{t+1} = a x_t + c_t.
// (unchanged from the validated round-3 version; plain cached loads)
// ---------------------------------------------------------------------------
__global__ __launch_bounds__(BLK) void compose_kernel(
    const float* __restrict__ eps_x,
    const float* __restrict__ u_a,
    const float* __restrict__ sigmasq,
    const float* __restrict__ eps_mu,
    const float* __restrict__ eps_x0,
    double Fa, double dF,
    double2* __restrict__ comp,       // [NSEG-1][S]
    double* __restrict__ params)      // [S][4] = a,b,sd,x0
{
    const int bid = blockIdx.x;
    const int s   = bid >> 2;
    const int seg = bid & 3;
    if (seg == NSEG - 1) return;      // seg 3's composition is never consumed
    const int tid  = threadIdx.x;
    const int lane = tid & 63;
    const int wid  = tid >> 6;

    __shared__ double  pl[3];
    __shared__ double2 wtot[NW];

    const size_t base = (size_t)s * T_TR + (size_t)seg * SEGT + (size_t)tid * CH;

    // issue loads first so the param chain hides under them
    const f4* e4 = (const f4*)(eps_x + base);
    f4 v0 = e4[0];
    f4 v1 = e4[1];

    if (tid < 64) {
        double a, b, sd, x0;
        param_chain(Fa, dF, u_a[s], sigmasq[s], eps_mu[s], eps_x0[s], a, b, sd, x0);
        if (tid == 0) {
            pl[0] = a; pl[1] = b; pl[2] = sd;
            if (seg == 0) {
                params[4*s+0] = a;  params[4*s+1] = b;
                params[4*s+2] = sd; params[4*s+3] = x0;
            }
        }
    }
    __syncthreads();
    const double a = pl[0], b = pl[1], sd = pl[2];

    float ev[CH];
    ev[0]=v0.x; ev[1]=v0.y; ev[2]=v0.z; ev[3]=v0.w;
    ev[4]=v1.x; ev[5]=v1.y; ev[6]=v1.z; ev[7]=v1.w;

    double A = 1.0, Bv = 0.0;
    #pragma unroll
    for (int j = 0; j < CH; ++j) {
        double c = fma(sd, (double)ev[j], b);
        Bv = fma(a, Bv, c);
        A *= a;
    }

    // ordered wave reduce (earliest lane first); lane 0 holds wave total
    #pragma unroll
    for (int off = 1; off < 64; off <<= 1) {
        double pA = __shfl_down(A, off);
        double pB = __shfl_down(Bv, off);
        Bv = fma(pA, Bv, pB);     // later ∘ earlier
        A  = pA * A;
    }
    if (lane == 0) wtot[wid] = make_double2(A, Bv);
    __syncthreads();
    if (tid == 0) {
        double CA = wtot[0].x, CB = wtot[0].y;
        #pragma unroll
        for (int w = 1; w < NW; ++w) {
            CB = fma(wtot[w].x, CB, wtot[w].y);
            CA = wtot[w].x * CA;
        }
        comp[seg * S_SUB + s] = make_double2(CA, CB);
    }
}

// ---------------------------------------------------------------------------
// Kernel 2: fused seed-chain + scan + replay->LDS + coalesced logits phase.
// Phase A (scan + replay) keeps the exact f64 math of the validated kernel
// and deposits x_t (f64) into a pad-9 LDS transpose buffer.
// Phase B remaps trial = j*BLK + tid so inputs/u_bern/stores are fully
// lane-dense coalesced. eps_x is read only in phase A.
// ---------------------------------------------------------------------------
__global__ __launch_bounds__(BLK, 8) void fused_kernel(
    const float* __restrict__ inputs,
    const float* __restrict__ eps_w,
    const float* __restrict__ eps_x,
    const float* __restrict__ u_bern,
    const double* __restrict__ params,
    const double2* __restrict__ comp,
    float* __restrict__ out_x,
    float* __restrict__ out_y)
{
    const int bid  = blockIdx.x;
    const int s    = bid >> 2;
    const int seg  = bid & 3;
    const int tid  = threadIdx.x;
    const int lane = tid & 63;
    const int wid  = tid >> 6;

    __shared__ double2 wtot[NW];
    __shared__ double  xs[BLK * (CH + 1)];   // pad-9 transpose buffer (18 KiB)

    const size_t segbase = (size_t)s * T_TR + (size_t)seg * SEGT;
    const size_t base    = segbase + (size_t)tid * CH;

    // eps_x chunk (phase-A only)
    const f4* e4 = (const f4*)(eps_x + base);
    f4 ev0 = e4[0];
    f4 ev1 = e4[1];

    // block-uniform parameters + inline seed chain (L2-hot, <=3 fma)
    const double a  = params[4*s+0];
    const double b  = params[4*s+1];
    const double sd = params[4*s+2];
    double xseed    = params[4*s+3];
    for (int i = 0; i < seg; ++i) {
        double2 c = comp[i * S_SUB + s];
        xseed = fma(c.x, xseed, c.y);
    }

    const float* wp = eps_w + s * D_IN;
    const double w0 = (double)wp[0], w1 = (double)wp[1];
    const double w2 = (double)wp[2], w3 = (double)wp[3];
    const double w4 = (double)wp[4], w5 = (double)wp[5];
    const double w6 = (double)wp[6], w7 = (double)wp[7];

    float ev[CH];
    ev[0]=ev0.x; ev[1]=ev0.y; ev[2]=ev0.z; ev[3]=ev0.w;
    ev[4]=ev1.x; ev[5]=ev1.y; ev[6]=ev1.z; ev[7]=ev1.w;

    // ---- phase 1: local affine compose over the chunk ----
    double A = 1.0, Bv = 0.0;
    #pragma unroll
    for (int j = 0; j < CH; ++j) {
        double c = fma(sd, (double)ev[j], b);
        Bv = fma(a, Bv, c);
        A *= a;
    }

    // ---- phase 2a: inclusive wave scan (shfl_up Hillis-Steele) ----
    #pragma unroll
    for (int off = 1; off < 64; off <<= 1) {
        double pA = __shfl_up(A, off);
        double pB = __shfl_up(Bv, off);
        if (lane >= off) {
            Bv = fma(A, pB, Bv);   // cur ∘ prev
            A  = A * pA;
        }
    }
    if (lane == 63) wtot[wid] = make_double2(A, Bv);
    __syncthreads();

    // ---- phase 2b: exclusive cross-wave prefix ----
    double PA = 1.0, PB = 0.0;
    for (int w = 0; w < wid; ++w) {
        double2 t = wtot[w];
        PB = fma(t.x, PB, t.y);
        PA = t.x * PA;
    }
    double eA = __shfl_up(A, 1);
    double eB = __shfl_up(Bv, 1);
    if (lane == 0) { eA = 1.0; eB = 0.0; }
    double EB = fma(eA, PB, eB);
    double EA = eA * PA;
    double x  = fma(EA, xseed, EB);   // x at start of this thread's chunk

    // ---- phase A replay: deposit x_t (f64, pre-update) into LDS ----
    #pragma unroll
    for (int j = 0; j < CH; ++j) {
        xs[tid * (CH + 1) + j] = x;
        double c = fma(sd, (double)ev[j], b);
        x = fma(a, x, c);
    }
    __syncthreads();

    // ---- phase B: coalesced streaming (trial = j*BLK + tid) ----
    float uv[CH];
    #pragma unroll
    for (int j = 0; j < CH; ++j)
        uv[j] = u_bern[segbase + j * BLK + tid];

    const f4* in4 = (const f4*)(inputs + segbase * D_IN);
    #pragma unroll
    for (int j = 0; j < CH; ++j) {
        const int t = j * BLK + tid;
        f4 i0 = in4[2*t];
        f4 i1 = in4[2*t + 1];
        double xv = xs[(t >> 3) * (CH + 1) + (t & 7)];
        double dot = fma((double)i0.x, w0,
                     fma((double)i0.y, w1,
                     fma((double)i0.z, w2,
                     fma((double)i0.w, w3,
                     fma((double)i1.x, w4,
                     fma((double)i1.y, w5,
                     fma((double)i1.z, w6, (double)i1.w * w7)))))));
        double L = xv + dot;
        double E = exp(-L);
        out_y[segbase + t] = ((double)uv[j] * (1.0 + E) < 1.0) ? 1.0f : 0.0f;
        out_x[segbase + t] = (float)xv;
    }
}

extern "C" void kernel_launch(void* const* d_in, const int* in_sizes, int n_in,
                              void* d_out, int out_size, void* d_ws, size_t ws_size,
                              hipStream_t stream) {
    const float* inputs  = (const float*)d_in[0];   // [S,T,D]
    const float* eps_w   = (const float*)d_in[1];   // [S,D]
    const float* u_a     = (const float*)d_in[2];   // [S]
    const float* sigmasq = (const float*)d_in[3];   // [S]
    const float* eps_mu  = (const float*)d_in[4];   // [S]
    const float* eps_x0  = (const float*)d_in[5];   // [S]
    const float* eps_x   = (const float*)d_in[6];   // [S,T]
    const float* u_bern  = (const float*)d_in[7];   // [S,T]

    float* out = (float*)d_out;                     // [x | y] f32

    double*  params = (double*)d_ws;                          // 16 KiB
    double2* comp   = (double2*)((char*)d_ws + 16*1024);      // 24 KiB used

    // input-independent truncation constants, computed on host (f64 libm)
    const double RS2 = 0.7071067811865476;
    const double Fa  = 0.5 * erfc(9.9 * RS2);       // Phi(-9.9)
    const double Fb  = 0.5 * erfc(-0.1 * RS2);      // Phi(0.1)
    const double dF  = Fb - Fa;

    compose_kernel<<<S_SUB*NSEG, BLK, 0, stream>>>(eps_x, u_a, sigmasq, eps_mu,
                                                   eps_x0, Fa, dF, comp, params);
    fused_kernel<<<S_SUB*NSEG, BLK, 0, stream>>>(inputs, eps_w, eps_x, u_bern,
                                                 params, comp,
                                                 out, out + (size_t)S_SUB * T_TR);
}